// Round 11
// baseline (684.351 us; speedup 1.0000x reference)
//
#include <hip/hip_runtime.h>
#include <hip/hip_bf16.h>

// TransNormer: causal linear attention, B=2 N=2048 D=2048 H=16 I=1 K=V=128.
// Precision: all tensors single-plane fp16, 1-pass mfma_f32_16x16x32_f16,
// fp32 accumulation (measured absmax 0.03125 vs threshold 0.109).
// R11: merged qkv GEMM = 256^2 tile, 8 waves, REG-STAGED 2-deep pipeline
// (T14+T4): loads for tile kt+2 issued into registers at top of tile kt;
// ds_write of tile kt+1 at tile end -- the compiler's dependency wait there is
// COUNTED (kt+2's 8 loads stay in flight across raw s_barriers). 4 phases/tile,
// 2 barriers/phase, setprio around MFMA (m201 template shape).

typedef _Float16 f16x8 __attribute__((ext_vector_type(8)));
typedef _Float16 f16x4 __attribute__((ext_vector_type(4)));
typedef float    f32x4 __attribute__((ext_vector_type(4)));

#define DEV static __device__ __forceinline__

// XOR swizzle of byte bits 4-6 (bank-group spread); 16B blocks are atomic.
DEV int swzx(int row) { return (((row & 7) ^ ((row >> 3) & 7)) << 4); }

typedef const unsigned int __attribute__((address_space(1)))* gas_t;
typedef unsigned int __attribute__((address_space(3)))* las_t;
DEV void gld16(const void* g, void* l) {   // global -> LDS DMA, 16B/lane
  __builtin_amdgcn_global_load_lds((gas_t)g, (las_t)l, 16, 0, 0);
}

// ---------------- cast fp32 -> fp16, contiguous ----------------
__global__ void k_cast_h(const float* __restrict__ in, _Float16* __restrict__ out, int n) {
  int i = (blockIdx.x * blockDim.x + threadIdx.x) * 4;
  int stride = gridDim.x * blockDim.x * 4;
  for (; i < n; i += stride) {
    float4 v = *reinterpret_cast<const float4*>(in + i);
    f16x4 o;
    o[0] = (_Float16)v.x; o[1] = (_Float16)v.y;
    o[2] = (_Float16)v.z; o[3] = (_Float16)v.w;
    *reinterpret_cast<f16x4*>(out + i) = o;
  }
}

// --- 4 weight transposes in one dispatch: out[c][r] = fp16(in[r][c]) ---
__global__ void k_transpose_h4(const float* __restrict__ w0, const float* __restrict__ w1,
                               const float* __restrict__ w2, const float* __restrict__ w3,
                               _Float16* __restrict__ o0, _Float16* __restrict__ o1,
                               _Float16* __restrict__ o2, _Float16* __restrict__ o3) {
  __shared__ float tile[32][33];
  const float* in; _Float16* out;
  switch (blockIdx.z) {
    case 0: in = w0; out = o0; break;
    case 1: in = w1; out = o1; break;
    case 2: in = w2; out = o2; break;
    default: in = w3; out = o3; break;
  }
  int tx = threadIdx.x, ty = threadIdx.y;           // block (32,8)
  int c0 = blockIdx.x * 32, r0 = blockIdx.y * 32;
  #pragma unroll
  for (int j = 0; j < 4; ++j)
    tile[ty + j * 8][tx] = in[(size_t)(r0 + ty + j * 8) * 2048 + c0 + tx];
  __syncthreads();
  #pragma unroll
  for (int j = 0; j < 4; ++j)
    out[(size_t)(c0 + ty + j * 8) * 2048 + r0 + tx] = (_Float16)tile[tx][ty + j * 8];
}

// --- batched transpose: v = qkv[:, 4096+h*128 .. ] (stride 6144) -> (bh,v,n) ---
__global__ void k_transpose_v(const _Float16* __restrict__ in, _Float16* __restrict__ out) {
  __shared__ _Float16 tile[32][33];
  int tx = threadIdx.x, ty = threadIdx.y;           // block (32,8)
  int v0 = blockIdx.x * 32, n0 = blockIdx.y * 32, bh = blockIdx.z;
  int b = bh >> 4, h = bh & 15;
  #pragma unroll
  for (int j = 0; j < 4; ++j)
    tile[ty + j * 8][tx] =
        in[(size_t)(b * 2048 + n0 + ty + j * 8) * 6144 + 4096 + h * 128 + v0 + tx];
  __syncthreads();
  #pragma unroll
  for (int j = 0; j < 4; ++j)
    out[((size_t)bh * 128 + v0 + ty + j * 8) * 2048 + n0 + tx] = tile[tx][ty + j * 8];
}

// ---- 256^2 GEMM: C[4096][6144] = A[4096][2048] * B[6144][2048]^T, fp16 ----
// 8 waves (2M x 4N), BK=64, reg-staged 2-deep counted pipeline, 128KB LDS.
__global__ __launch_bounds__(512, 2) void k_gemm256(const _Float16* __restrict__ A,
                                                    const _Float16* __restrict__ B,
                                                    _Float16* __restrict__ C, int ldc) {
  __shared__ __align__(16) _Float16 Ab[2][256 * 64];   // 32KB x2
  __shared__ __align__(16) _Float16 Bb[2][256 * 64];   // 32KB x2
  const int tid = threadIdx.x;
  const int lane = tid & 63, w = tid >> 6;             // 8 waves
  const int lr = lane & 15, lg = lane >> 4;
  const int bm = blockIdx.y, bn = blockIdx.x;
  const int wr = (w >> 2) * 128, wc = (w & 3) * 64;    // wave tile 128x64

  f32x4 acc[8][4];
  #pragma unroll
  for (int i = 0; i < 8; ++i)
    #pragma unroll
    for (int j = 0; j < 4; ++j) { f32x4 z = {0.f, 0.f, 0.f, 0.f}; acc[i][j] = z; }

  const _Float16* aBase = A + (size_t)(bm * 256) * 2048;
  const _Float16* bBase = B + (size_t)(bn * 256) * 2048;

  const int srow = tid >> 3, sc8 = tid & 7;            // staging: 64 rows/it, 8 chunks

  f32x4 rA0[4], rB0[4], rA1[4], rB1[4];                // two named reg sets (static idx)

  auto ISSUE = [&](int kt, f32x4* ra, f32x4* rb) {     // global -> regs (8 dwordx4)
    #pragma unroll
    for (int it = 0; it < 4; ++it) {
      int row = it * 64 + srow;
      int cb  = (sc8 * 16) ^ swzx(row);                // pre-swizzled source col (bytes)
      size_t g = (size_t)row * 2048 + kt * 64 + (cb >> 1);
      ra[it] = *reinterpret_cast<const f32x4*>(aBase + g);
      rb[it] = *reinterpret_cast<const f32x4*>(bBase + g);
    }
  };
  auto WRITE = [&](int c, const f32x4* ra, const f32x4* rb) {  // regs -> LDS, linear
    #pragma unroll
    for (int it = 0; it < 4; ++it) {
      int ld = it * 8192 + tid * 16;                   // 64 rows x 128 B per it
      *reinterpret_cast<f32x4*>((char*)Ab[c] + ld) = ra[it];
      *reinterpret_cast<f32x4*>((char*)Bb[c] + ld) = rb[it];
    }
  };
  auto PHASES = [&](int c) {                           // 4 x {ds_read, bar, MFMA, bar}
    f16x8 bf[4];
    #pragma unroll
    for (int p = 0; p < 4; ++p) {
      const int ks = p >> 1, mh = p & 1;
      if (mh == 0) {                                   // new ks: reload B frags
        #pragma unroll
        for (int nj = 0; nj < 4; ++nj) {
          int br = wc + nj * 16 + lr;
          bf[nj] = *reinterpret_cast<const f16x8*>(
              (const char*)Bb[c] + br * 128 + ((ks * 64 + lg * 16) ^ swzx(br)));
        }
      }
      f16x8 af[4];
      #pragma unroll
      for (int m4 = 0; m4 < 4; ++m4) {
        int ar = wr + mh * 64 + m4 * 16 + lr;
        af[m4] = *reinterpret_cast<const f16x8*>(
            (const char*)Ab[c] + ar * 128 + ((ks * 64 + lg * 16) ^ swzx(ar)));
      }
      __builtin_amdgcn_s_barrier();                    // align waves: LDS burst done
      __builtin_amdgcn_s_setprio(1);
      #pragma unroll
      for (int m4 = 0; m4 < 4; ++m4)
        #pragma unroll
        for (int nj = 0; nj < 4; ++nj)
          acc[mh * 4 + m4][nj] =
              __builtin_amdgcn_mfma_f32_16x16x32_f16(af[m4], bf[nj], acc[mh * 4 + m4][nj], 0, 0, 0);
      __builtin_amdgcn_s_setprio(0);
      __builtin_amdgcn_s_barrier();
      __builtin_amdgcn_sched_barrier(0);
    }
  };

  // prologue: tiles 0,1 -> regs; tile 0 -> LDS[0]
  ISSUE(0, rA0, rB0);
  ISSUE(1, rA1, rB1);
  __builtin_amdgcn_sched_barrier(0);
  WRITE(0, rA0, rB0);                                  // compiler: counted vmcnt (rA0 only)
  asm volatile("s_waitcnt lgkmcnt(0)" ::: "memory");   // cross-wave ds_write visibility
  __builtin_amdgcn_s_barrier();
  __builtin_amdgcn_sched_barrier(0);

  for (int kt = 0; kt < 32; kt += 2) {
    // ---- tile kt (LDS[0]); prefetch kt+2 -> rA0 (its old content already in LDS)
    if (kt + 2 < 32) ISSUE(kt + 2, rA0, rB0);
    __builtin_amdgcn_sched_barrier(0);
    PHASES(0);
    WRITE(1, rA1, rB1);                                // waits rA1 only; rA0 stays in flight
    asm volatile("s_waitcnt lgkmcnt(0)" ::: "memory");
    __builtin_amdgcn_s_barrier();
    __builtin_amdgcn_sched_barrier(0);

    // ---- tile kt+1 (LDS[1]); prefetch kt+3 -> rA1
    if (kt + 3 < 32) ISSUE(kt + 3, rA1, rB1);
    __builtin_amdgcn_sched_barrier(0);
    PHASES(1);
    if (kt + 2 < 32) {
      WRITE(0, rA0, rB0);                              // waits rA0 only; rA1 in flight
      asm volatile("s_waitcnt lgkmcnt(0)" ::: "memory");
      __builtin_amdgcn_s_barrier();
      __builtin_amdgcn_sched_barrier(0);
    }
  }

  #pragma unroll
  for (int mi = 0; mi < 8; ++mi)
    #pragma unroll
    for (int nj = 0; nj < 4; ++nj)
      #pragma unroll
      for (int r = 0; r < 4; ++r) {
        int grow = bm * 256 + wr + mi * 16 + lg * 4 + r;   // D row = (lane>>4)*4+r
        int gcol = bn * 256 + wc + nj * 16 + lr;           // D col = lane&15
        C[(size_t)grow * ldc + gcol] = (_Float16)acc[mi][nj][r];
      }
}

// ---- GEMM 128^2 (final projection): C[4096][2048] fp32 = y * woT^T ----
__global__ __launch_bounds__(256) void k_gemm1(const _Float16* __restrict__ A,
                                               const _Float16* __restrict__ B,
                                               float* __restrict__ C, int ldc) {
  __shared__ __align__(16) _Float16 As[128 * 64];
  __shared__ __align__(16) _Float16 Bs[128 * 64];
  const int tid = threadIdx.x;
  const int lane = tid & 63, w = tid >> 6;
  const int lr = lane & 15, lg = lane >> 4;
  const int bm = blockIdx.y, bn = blockIdx.x;
  const int wr = (w >> 1) * 64, wc = (w & 1) * 64;

  f32x4 acc[4][4];
  #pragma unroll
  for (int i = 0; i < 4; ++i)
    #pragma unroll
    for (int j = 0; j < 4; ++j) { f32x4 z = {0.f, 0.f, 0.f, 0.f}; acc[i][j] = z; }

  const size_t aOff = (size_t)(bm * 128) * 2048;
  const size_t bOff = (size_t)(bn * 128) * 2048;

  for (int kt = 0; kt < 32; ++kt) {
    __syncthreads();                               // prev readers done
    #pragma unroll
    for (int it = 0; it < 4; ++it) {               // 16B/lane DMA, lane-linear dest
      int row = it * 32 + (tid >> 3);
      int cb  = ((tid & 7) * 16) ^ swzx(row);      // pre-swizzled source col (bytes)
      size_t g = (size_t)row * 2048 + kt * 64 + (cb >> 1);
      int ld = it * 4096 + tid * 16;               // bytes: 32 rows x 128 B per it
      gld16(A + aOff + g, (char*)As + ld);
      gld16(B + bOff + g, (char*)Bs + ld);
    }
    __syncthreads();                               // drains vmcnt(0): DMA landed
    #pragma unroll
    for (int ks = 0; ks < 2; ++ks) {
      f16x8 af[4], bf[4];
      #pragma unroll
      for (int f = 0; f < 4; ++f) {
        int ar = wr + f * 16 + lr;
        af[f] = *reinterpret_cast<const f16x8*>((const char*)As + ar * 128 +
                                                ((ks * 64 + lg * 16) ^ swzx(ar)));
        int br = wc + f * 16 + lr;
        bf[f] = *reinterpret_cast<const f16x8*>((const char*)Bs + br * 128 +
                                                ((ks * 64 + lg * 16) ^ swzx(br)));
      }
      __builtin_amdgcn_s_setprio(1);
      #pragma unroll
      for (int i = 0; i < 4; ++i)
        #pragma unroll
        for (int j = 0; j < 4; ++j)
          acc[i][j] = __builtin_amdgcn_mfma_f32_16x16x32_f16(af[i], bf[j], acc[i][j], 0, 0, 0);
      __builtin_amdgcn_s_setprio(0);
    }
  }

  #pragma unroll
  for (int fm = 0; fm < 4; ++fm)
    #pragma unroll
    for (int fn = 0; fn < 4; ++fn)
      #pragma unroll
      for (int r = 0; r < 4; ++r) {
        int grow = bm * 128 + wr + fm * 16 + lg * 4 + r;
        int gcol = bn * 128 + wc + fn * 16 + lr;
        C[(size_t)grow * ldc + gcol] = acc[fm][fn][r];
      }
}

// ---------------- fused masked attention + RMSNorm, fp16 1-pass ----------
// 4 waves (256 thr), QBLK=64, KVBLK=64. grid (32, 16): block j does q-tiles
// {j, 31-j} -> uniform 33 KV-tile-units; 512 blocks = 2/CU co-resident.
__global__ __launch_bounds__(256) void k_attn1(const _Float16* __restrict__ qkv,
                                               const _Float16* __restrict__ vt,
                                               const float* __restrict__ nm,
                                               const float* __restrict__ rms_scale,
                                               _Float16* __restrict__ y) {
  __shared__ __align__(16) _Float16 Ks[2][64 * 128];   // [m][k] 16KB x2
  __shared__ __align__(16) _Float16 Vs[2][128 * 64];   // [v][m] 16KB x2
  __shared__ __align__(16) _Float16 Ps[64 * 64];       // [n][m] 8KB
  const int tid = threadIdx.x;
  const int lane = tid & 63, w = tid >> 6;             // w in 0..3
  const int lr = lane & 15, lg = lane >> 4;
  const int bh = blockIdx.x, b = bh >> 4, h = bh & 15;
  const _Float16* qb = qkv + (size_t)b * 2048 * 6144 + h * 128;          // q cols
  const _Float16* kb = qkv + (size_t)b * 2048 * 6144 + 2048 + h * 128;   // k cols
  const size_t vbase = (size_t)bh * 128 * 2048;                          // (bh,v,n)

  const int krow = tid >> 4, kc = tid & 15;    // K stage: 16 rows/it, 16 chunks
  const int vrow = tid >> 3, vc = tid & 7;     // V stage: 32 rows/it, 8 chunks

  auto STAGE = [&](int t, int bufi) {
    #pragma unroll
    for (int it = 0; it < 4; ++it) {
      int kr = it * 16 + krow;
      int gk = ((kc * 16) ^ swzx(kr)) >> 1;
      gld16(kb + (size_t)(t * 64 + kr) * 6144 + gk,
            (char*)Ks[bufi] + it * 4096 + tid * 16);   // 16 rows x 256 B per it
      int vr = it * 32 + vrow;
      int gv = ((vc * 16) ^ swzx(vr)) >> 1;
      gld16(vt + vbase + (size_t)vr * 2048 + t * 64 + gv,
            (char*)Vs[bufi] + it * 4096 + tid * 16);   // 32 rows x 128 B per it
    }
  };

  #pragma unroll
  for (int pi = 0; pi < 2; ++pi) {
    const int qt = pi ? (31 - (int)blockIdx.y) : (int)blockIdx.y;  // 64-row q-tile
    const int nT = qt + 1;

    f16x8 aq[4];
    {
      const _Float16* qrow = qb + (size_t)(qt * 64 + w * 16 + lr) * 6144;
      #pragma unroll
      for (int ks = 0; ks < 4; ++ks)
        aq[ks] = *reinterpret_cast<const f16x8*>(qrow + ks * 32 + lg * 8);
    }

    f32x4 accY[8];
    #pragma unroll
    for (int i = 0; i < 8; ++i) { f32x4 z = {0.f, 0.f, 0.f, 0.f}; accY[i] = z; }

    STAGE(0, 0);
    asm volatile("s_waitcnt vmcnt(0)" ::: "memory");
    __builtin_amdgcn_s_barrier();
    __builtin_amdgcn_sched_barrier(0);

    for (int t = 0; t < nT; ++t) {
      const int cur = t & 1;

      float nmv[4][4];                            // mask for tile t -- FIRST
      #pragma unroll
      for (int fm = 0; fm < 4; ++fm)
        #pragma unroll
        for (int r = 0; r < 4; ++r)
          nmv[fm][r] = nm[(size_t)(qt * 64 + w * 16 + lg * 4 + r) * 2048 +
                          t * 64 + fm * 16 + lr];
      __builtin_amdgcn_sched_barrier(0);          // pin: nm loads before DMA

      if (t + 1 < nT) STAGE(t + 1, cur ^ 1);      // DMA overlaps compute below

      f32x4 accS[4];
      #pragma unroll
      for (int i = 0; i < 4; ++i) { f32x4 z = {0.f, 0.f, 0.f, 0.f}; accS[i] = z; }
      __builtin_amdgcn_s_setprio(1);
      #pragma unroll
      for (int ks = 0; ks < 4; ++ks) {
        #pragma unroll
        for (int fm = 0; fm < 4; ++fm) {
          int br = fm * 16 + lr;
          f16x8 bk = *reinterpret_cast<const f16x8*>(
              (const char*)Ks[cur] + br * 256 + ((ks * 64 + lg * 16) ^ swzx(br)));
          accS[fm] = __builtin_amdgcn_mfma_f32_16x16x32_f16(aq[ks], bk, accS[fm], 0, 0, 0);
        }
      }
      __builtin_amdgcn_s_setprio(0);

      #pragma unroll
      for (int fm = 0; fm < 4; ++fm)
        #pragma unroll
        for (int r = 0; r < 4; ++r) {
          float pv = accS[fm][r] * nmv[fm][r];
          int pr = w * 16 + lg * 4 + r, pc = fm * 16 + lr;
          *reinterpret_cast<_Float16*>((char*)Ps + pr * 128 + ((pc * 2) ^ swzx(pr))) =
              (_Float16)pv;
        }

      __builtin_amdgcn_s_setprio(1);
      #pragma unroll
      for (int ks = 0; ks < 2; ++ks) {
        int ar = w * 16 + lr;
        f16x8 ap = *reinterpret_cast<const f16x8*>(
            (const char*)Ps + ar * 128 + ((ks * 64 + lg * 16) ^ swzx(ar)));
        #pragma unroll
        for (int fv = 0; fv < 8; ++fv) {
          int br = fv * 16 + lr;
          f16x8 bv = *reinterpret_cast<const f16x8*>(
              (const char*)Vs[cur] + br * 128 + ((ks * 64 + lg * 16) ^ swzx(br)));
          accY[fv] = __builtin_amdgcn_mfma_f32_16x16x32_f16(ap, bv, accY[fv], 0, 0, 0);
        }
      }
      __builtin_amdgcn_s_setprio(0);

      asm volatile("s_waitcnt vmcnt(0)" ::: "memory");
      __builtin_amdgcn_s_barrier();
      __builtin_amdgcn_sched_barrier(0);
    }

    // epilogue: RMSNorm over V=128 per row, write y fp16 (b,n,h,v)
    #pragma unroll
    for (int r = 0; r < 4; ++r) {
      float sq = 0.f;
      #pragma unroll
      for (int fv = 0; fv < 8; ++fv) { float yy = accY[fv][r]; sq += yy * yy; }
      sq += __shfl_xor(sq, 1); sq += __shfl_xor(sq, 2);
      sq += __shfl_xor(sq, 4); sq += __shfl_xor(sq, 8);
      float scale = rsqrtf(sq * (1.0f / 128.0f) + 1e-6f);
      int nrow = qt * 64 + w * 16 + lg * 4 + r;
      size_t orow = ((size_t)b * 2048 + nrow) * 2048 + (size_t)h * 128;
      #pragma unroll
      for (int fv = 0; fv < 8; ++fv) {
        int col = fv * 16 + lr;
        y[orow + col] = (_Float16)(accY[fv][r] * scale * rms_scale[col]);
      }
    }
  }
}

extern "C" void kernel_launch(void* const* d_in, const int* in_sizes, int n_in,
                              void* d_out, int out_size, void* d_ws, size_t ws_size,
                              hipStream_t stream) {
  (void)in_sizes; (void)n_in; (void)out_size; (void)ws_size;
  const float* x  = (const float*)d_in[0];
  const float* nm = (const float*)d_in[1];
  const float* wq = (const float*)d_in[2];
  const float* wk = (const float*)d_in[3];
  const float* wv = (const float*)d_in[4];
  const float* rs = (const float*)d_in[5];
  const float* wo = (const float*)d_in[6];

  _Float16* p = (_Float16*)d_ws;                 // ~118 MB of fp16 planes
  _Float16* xf  = p; p += 8388608;               // x fp16; reused as y after attn
  _Float16* wt3 = p; p += 12582912;              // [wqT; wkT; wvT] (6144 x 2048)
  _Float16* wto = p; p += 4194304;               // woT
  _Float16* qkv = p; p += 25165824;              // (b,n) x (q|k|v) (4096 x 6144)
  _Float16* vtf = p; p += 8388608;               // v^T (b*h, v, n)

  k_cast_h<<<dim3(2048), dim3(256), 0, stream>>>(x, xf, 8388608);

  k_transpose_h4<<<dim3(64, 64, 4), dim3(32, 8), 0, stream>>>(
      wq, wk, wv, wo, wt3, wt3 + 4194304, wt3 + 8388608, wto);

  // merged q|k|v projection: C (4096 x 6144), 256^2 tiles, reg-staged pipeline
  k_gemm256<<<dim3(24, 16), dim3(512), 0, stream>>>(xf, wt3, qkv, 6144);
  k_transpose_v<<<dim3(4, 64, 32), dim3(32, 8), 0, stream>>>(qkv, vtf);

  // y written into the (now dead) x plane
  k_attn1<<<dim3(32, 16), dim3(256), 0, stream>>>(qkv, vtf, nm, rs, xf);

  k_gemm1<<<dim3(16, 32), dim3(256), 0, stream>>>(xf, wto, (float*)d_out, 2048);
}

// Round 12
// 271.297 us; speedup vs baseline: 2.5225x; 2.5225x over previous
//
#include <hip/hip_runtime.h>
#include <hip/hip_bf16.h>

// TransNormer: causal linear attention, B=2 N=2048 D=2048 H=16 I=1 K=V=128.
// Precision: all tensors single-plane fp16, 1-pass mfma_f32_16x16x32_f16,
// fp32 accumulation (measured absmax 0.03125 vs threshold 0.109).
// R12: revert to R9's proven 128^2 GEMM structure (R10/R11 256^2 experiments
// regressed: drain-0 pipeline, then VGPR spill). New: GEMM LDS double-buffer
// with attn-style pipeline -- STAGE(kt+1) issued at tile top, compute tile kt,
// vmcnt(0)+barrier at tile END (DMA latency hidden under 32 MFMAs).

typedef _Float16 f16x8 __attribute__((ext_vector_type(8)));
typedef _Float16 f16x4 __attribute__((ext_vector_type(4)));
typedef float    f32x4 __attribute__((ext_vector_type(4)));

#define DEV static __device__ __forceinline__

// XOR swizzle of byte bits 4-6 (bank-group spread); 16B blocks are atomic.
DEV int swzx(int row) { return (((row & 7) ^ ((row >> 3) & 7)) << 4); }

typedef const unsigned int __attribute__((address_space(1)))* gas_t;
typedef unsigned int __attribute__((address_space(3)))* las_t;
DEV void gld16(const void* g, void* l) {   // global -> LDS DMA, 16B/lane
  __builtin_amdgcn_global_load_lds((gas_t)g, (las_t)l, 16, 0, 0);
}

// ---------------- cast fp32 -> fp16, contiguous ----------------
__global__ void k_cast_h(const float* __restrict__ in, _Float16* __restrict__ out, int n) {
  int i = (blockIdx.x * blockDim.x + threadIdx.x) * 4;
  int stride = gridDim.x * blockDim.x * 4;
  for (; i < n; i += stride) {
    float4 v = *reinterpret_cast<const float4*>(in + i);
    f16x4 o;
    o[0] = (_Float16)v.x; o[1] = (_Float16)v.y;
    o[2] = (_Float16)v.z; o[3] = (_Float16)v.w;
    *reinterpret_cast<f16x4*>(out + i) = o;
  }
}

// --- 4 weight transposes in one dispatch: out[c][r] = fp16(in[r][c]) ---
__global__ void k_transpose_h4(const float* __restrict__ w0, const float* __restrict__ w1,
                               const float* __restrict__ w2, const float* __restrict__ w3,
                               _Float16* __restrict__ o0, _Float16* __restrict__ o1,
                               _Float16* __restrict__ o2, _Float16* __restrict__ o3) {
  __shared__ float tile[32][33];
  const float* in; _Float16* out;
  switch (blockIdx.z) {
    case 0: in = w0; out = o0; break;
    case 1: in = w1; out = o1; break;
    case 2: in = w2; out = o2; break;
    default: in = w3; out = o3; break;
  }
  int tx = threadIdx.x, ty = threadIdx.y;           // block (32,8)
  int c0 = blockIdx.x * 32, r0 = blockIdx.y * 32;
  #pragma unroll
  for (int j = 0; j < 4; ++j)
    tile[ty + j * 8][tx] = in[(size_t)(r0 + ty + j * 8) * 2048 + c0 + tx];
  __syncthreads();
  #pragma unroll
  for (int j = 0; j < 4; ++j)
    out[(size_t)(c0 + ty + j * 8) * 2048 + r0 + tx] = (_Float16)tile[tx][ty + j * 8];
}

// --- batched transpose: v = qkv[:, 4096+h*128 .. ] (stride 6144) -> (bh,v,n) ---
__global__ void k_transpose_v(const _Float16* __restrict__ in, _Float16* __restrict__ out) {
  __shared__ _Float16 tile[32][33];
  int tx = threadIdx.x, ty = threadIdx.y;           // block (32,8)
  int v0 = blockIdx.x * 32, n0 = blockIdx.y * 32, bh = blockIdx.z;
  int b = bh >> 4, h = bh & 15;
  #pragma unroll
  for (int j = 0; j < 4; ++j)
    tile[ty + j * 8][tx] =
        in[(size_t)(b * 2048 + n0 + ty + j * 8) * 6144 + 4096 + h * 128 + v0 + tx];
  __syncthreads();
  #pragma unroll
  for (int j = 0; j < 4; ++j)
    out[((size_t)bh * 128 + v0 + ty + j * 8) * 2048 + n0 + tx] = tile[tx][ty + j * 8];
}

// ---- GEMM: C[4096][Nt*128] = A[4096][2048] * B[Nt*128][2048]^T, fp16 ----
// 128x128 tile, BK=64, 4 waves, double-buffered gld_lds pipeline (64KB LDS,
// 2 blocks/CU): STAGE(kt+1) at tile top, compute kt, drain at tile END.
// OUTF32: 1 -> fp32 C (d_out), 0 -> fp16 C. ldc = C row stride.
template <int OUTF32>
__global__ __launch_bounds__(256) void k_gemm_db(const _Float16* __restrict__ A,
                                                 const _Float16* __restrict__ B,
                                                 void* __restrict__ C, int ldc) {
  __shared__ __align__(16) _Float16 As[2][128 * 64];   // 16KB x2
  __shared__ __align__(16) _Float16 Bs[2][128 * 64];   // 16KB x2
  const int tid = threadIdx.x;
  const int lane = tid & 63, w = tid >> 6;
  const int lr = lane & 15, lg = lane >> 4;
  const int bm = blockIdx.y, bn = blockIdx.x;
  const int wr = (w >> 1) * 64, wc = (w & 1) * 64;

  f32x4 acc[4][4];
  #pragma unroll
  for (int i = 0; i < 4; ++i)
    #pragma unroll
    for (int j = 0; j < 4; ++j) { f32x4 z = {0.f, 0.f, 0.f, 0.f}; acc[i][j] = z; }

  const size_t aOff = (size_t)(bm * 128) * 2048;
  const size_t bOff = (size_t)(bn * 128) * 2048;

  auto STAGE = [&](int kt, int bufi) {
    #pragma unroll
    for (int it = 0; it < 4; ++it) {               // 16B/lane DMA, lane-linear dest
      int row = it * 32 + (tid >> 3);
      int cb  = ((tid & 7) * 16) ^ swzx(row);      // pre-swizzled source col (bytes)
      size_t g = (size_t)row * 2048 + kt * 64 + (cb >> 1);
      int ld = it * 4096 + tid * 16;               // bytes: 32 rows x 128 B per it
      gld16(A + aOff + g, (char*)As[bufi] + ld);
      gld16(B + bOff + g, (char*)Bs[bufi] + ld);
    }
  };

  STAGE(0, 0);
  asm volatile("s_waitcnt vmcnt(0)" ::: "memory");
  __builtin_amdgcn_s_barrier();
  __builtin_amdgcn_sched_barrier(0);

  for (int kt = 0; kt < 32; ++kt) {
    const int cur = kt & 1;
    if (kt + 1 < 32) STAGE(kt + 1, cur ^ 1);       // DMA overlaps compute below
    __builtin_amdgcn_sched_barrier(0);

    #pragma unroll
    for (int ks = 0; ks < 2; ++ks) {
      f16x8 af[4], bf[4];
      #pragma unroll
      for (int f = 0; f < 4; ++f) {
        int ar = wr + f * 16 + lr;
        af[f] = *reinterpret_cast<const f16x8*>((const char*)As[cur] + ar * 128 +
                                                ((ks * 64 + lg * 16) ^ swzx(ar)));
        int br = wc + f * 16 + lr;
        bf[f] = *reinterpret_cast<const f16x8*>((const char*)Bs[cur] + br * 128 +
                                                ((ks * 64 + lg * 16) ^ swzx(br)));
      }
      __builtin_amdgcn_s_setprio(1);
      #pragma unroll
      for (int i = 0; i < 4; ++i)
        #pragma unroll
        for (int j = 0; j < 4; ++j)
          acc[i][j] = __builtin_amdgcn_mfma_f32_16x16x32_f16(af[i], bf[j], acc[i][j], 0, 0, 0);
      __builtin_amdgcn_s_setprio(0);
    }

    // next tile's DMA landed (hidden under the 32 MFMAs above); rotate
    asm volatile("s_waitcnt vmcnt(0)" ::: "memory");
    __builtin_amdgcn_s_barrier();
    __builtin_amdgcn_sched_barrier(0);
  }

  #pragma unroll
  for (int fm = 0; fm < 4; ++fm)
    #pragma unroll
    for (int fn = 0; fn < 4; ++fn)
      #pragma unroll
      for (int r = 0; r < 4; ++r) {
        int grow = bm * 128 + wr + fm * 16 + lg * 4 + r;   // D row = (lane>>4)*4+r
        int gcol = bn * 128 + wc + fn * 16 + lr;           // D col = lane&15
        float v = acc[fm][fn][r];
        size_t o = (size_t)grow * ldc + gcol;
        if (OUTF32) ((float*)C)[o] = v;
        else        ((_Float16*)C)[o] = (_Float16)v;
      }
}

// ---------------- fused masked attention + RMSNorm, fp16 1-pass ----------
// 4 waves (256 thr), QBLK=64, KVBLK=64. grid (32, 16): block j does q-tiles
// {j, 31-j} -> uniform 33 KV-tile-units; 512 blocks = 2/CU co-resident.
__global__ __launch_bounds__(256) void k_attn1(const _Float16* __restrict__ qkv,
                                               const _Float16* __restrict__ vt,
                                               const float* __restrict__ nm,
                                               const float* __restrict__ rms_scale,
                                               _Float16* __restrict__ y) {
  __shared__ __align__(16) _Float16 Ks[2][64 * 128];   // [m][k] 16KB x2
  __shared__ __align__(16) _Float16 Vs[2][128 * 64];   // [v][m] 16KB x2
  __shared__ __align__(16) _Float16 Ps[64 * 64];       // [n][m] 8KB
  const int tid = threadIdx.x;
  const int lane = tid & 63, w = tid >> 6;             // w in 0..3
  const int lr = lane & 15, lg = lane >> 4;
  const int bh = blockIdx.x, b = bh >> 4, h = bh & 15;
  const _Float16* qb = qkv + (size_t)b * 2048 * 6144 + h * 128;          // q cols
  const _Float16* kb = qkv + (size_t)b * 2048 * 6144 + 2048 + h * 128;   // k cols
  const size_t vbase = (size_t)bh * 128 * 2048;                          // (bh,v,n)

  const int krow = tid >> 4, kc = tid & 15;    // K stage: 16 rows/it, 16 chunks
  const int vrow = tid >> 3, vc = tid & 7;     // V stage: 32 rows/it, 8 chunks

  auto STAGE = [&](int t, int bufi) {
    #pragma unroll
    for (int it = 0; it < 4; ++it) {
      int kr = it * 16 + krow;
      int gk = ((kc * 16) ^ swzx(kr)) >> 1;
      gld16(kb + (size_t)(t * 64 + kr) * 6144 + gk,
            (char*)Ks[bufi] + it * 4096 + tid * 16);   // 16 rows x 256 B per it
      int vr = it * 32 + vrow;
      int gv = ((vc * 16) ^ swzx(vr)) >> 1;
      gld16(vt + vbase + (size_t)vr * 2048 + t * 64 + gv,
            (char*)Vs[bufi] + it * 4096 + tid * 16);   // 32 rows x 128 B per it
    }
  };

  #pragma unroll
  for (int pi = 0; pi < 2; ++pi) {
    const int qt = pi ? (31 - (int)blockIdx.y) : (int)blockIdx.y;  // 64-row q-tile
    const int nT = qt + 1;

    f16x8 aq[4];
    {
      const _Float16* qrow = qb + (size_t)(qt * 64 + w * 16 + lr) * 6144;
      #pragma unroll
      for (int ks = 0; ks < 4; ++ks)
        aq[ks] = *reinterpret_cast<const f16x8*>(qrow + ks * 32 + lg * 8);
    }

    f32x4 accY[8];
    #pragma unroll
    for (int i = 0; i < 8; ++i) { f32x4 z = {0.f, 0.f, 0.f, 0.f}; accY[i] = z; }

    STAGE(0, 0);
    asm volatile("s_waitcnt vmcnt(0)" ::: "memory");
    __builtin_amdgcn_s_barrier();
    __builtin_amdgcn_sched_barrier(0);

    for (int t = 0; t < nT; ++t) {
      const int cur = t & 1;

      float nmv[4][4];                            // mask for tile t -- FIRST
      #pragma unroll
      for (int fm = 0; fm < 4; ++fm)
        #pragma unroll
        for (int r = 0; r < 4; ++r)
          nmv[fm][r] = nm[(size_t)(qt * 64 + w * 16 + lg * 4 + r) * 2048 +
                          t * 64 + fm * 16 + lr];
      __builtin_amdgcn_sched_barrier(0);          // pin: nm loads before DMA

      if (t + 1 < nT) STAGE(t + 1, cur ^ 1);      // DMA overlaps compute below

      f32x4 accS[4];
      #pragma unroll
      for (int i = 0; i < 4; ++i) { f32x4 z = {0.f, 0.f, 0.f, 0.f}; accS[i] = z; }
      __builtin_amdgcn_s_setprio(1);
      #pragma unroll
      for (int ks = 0; ks < 4; ++ks) {
        #pragma unroll
        for (int fm = 0; fm < 4; ++fm) {
          int br = fm * 16 + lr;
          f16x8 bk = *reinterpret_cast<const f16x8*>(
              (const char*)Ks[cur] + br * 256 + ((ks * 64 + lg * 16) ^ swzx(br)));
          accS[fm] = __builtin_amdgcn_mfma_f32_16x16x32_f16(aq[ks], bk, accS[fm], 0, 0, 0);
        }
      }
      __builtin_amdgcn_s_setprio(0);

      #pragma unroll
      for (int fm = 0; fm < 4; ++fm)
        #pragma unroll
        for (int r = 0; r < 4; ++r) {
          float pv = accS[fm][r] * nmv[fm][r];
          int pr = w * 16 + lg * 4 + r, pc = fm * 16 + lr;
          *reinterpret_cast<_Float16*>((char*)Ps + pr * 128 + ((pc * 2) ^ swzx(pr))) =
              (_Float16)pv;
        }

      __builtin_amdgcn_s_setprio(1);
      #pragma unroll
      for (int ks = 0; ks < 2; ++ks) {
        int ar = w * 16 + lr;
        f16x8 ap = *reinterpret_cast<const f16x8*>(
            (const char*)Ps + ar * 128 + ((ks * 64 + lg * 16) ^ swzx(ar)));
        #pragma unroll
        for (int fv = 0; fv < 8; ++fv) {
          int br = fv * 16 + lr;
          f16x8 bv = *reinterpret_cast<const f16x8*>(
              (const char*)Vs[cur] + br * 128 + ((ks * 64 + lg * 16) ^ swzx(br)));
          accY[fv] = __builtin_amdgcn_mfma_f32_16x16x32_f16(ap, bv, accY[fv], 0, 0, 0);
        }
      }
      __builtin_amdgcn_s_setprio(0);

      asm volatile("s_waitcnt vmcnt(0)" ::: "memory");
      __builtin_amdgcn_s_barrier();
      __builtin_amdgcn_sched_barrier(0);
    }

    // epilogue: RMSNorm over V=128 per row, write y fp16 (b,n,h,v)
    #pragma unroll
    for (int r = 0; r < 4; ++r) {
      float sq = 0.f;
      #pragma unroll
      for (int fv = 0; fv < 8; ++fv) { float yy = accY[fv][r]; sq += yy * yy; }
      sq += __shfl_xor(sq, 1); sq += __shfl_xor(sq, 2);
      sq += __shfl_xor(sq, 4); sq += __shfl_xor(sq, 8);
      float scale = rsqrtf(sq * (1.0f / 128.0f) + 1e-6f);
      int nrow = qt * 64 + w * 16 + lg * 4 + r;
      size_t orow = ((size_t)b * 2048 + nrow) * 2048 + (size_t)h * 128;
      #pragma unroll
      for (int fv = 0; fv < 8; ++fv) {
        int col = fv * 16 + lr;
        y[orow + col] = (_Float16)(accY[fv][r] * scale * rms_scale[col]);
      }
    }
  }
}

extern "C" void kernel_launch(void* const* d_in, const int* in_sizes, int n_in,
                              void* d_out, int out_size, void* d_ws, size_t ws_size,
                              hipStream_t stream) {
  (void)in_sizes; (void)n_in; (void)out_size; (void)ws_size;
  const float* x  = (const float*)d_in[0];
  const float* nm = (const float*)d_in[1];
  const float* wq = (const float*)d_in[2];
  const float* wk = (const float*)d_in[3];
  const float* wv = (const float*)d_in[4];
  const float* rs = (const float*)d_in[5];
  const float* wo = (const float*)d_in[6];

  _Float16* p = (_Float16*)d_ws;                 // ~118 MB of fp16 planes
  _Float16* xf  = p; p += 8388608;               // x fp16; reused as y after attn
  _Float16* wt3 = p; p += 12582912;              // [wqT; wkT; wvT] (6144 x 2048)
  _Float16* wto = p; p += 4194304;               // woT
  _Float16* qkv = p; p += 25165824;              // (b,n) x (q|k|v) (4096 x 6144)
  _Float16* vtf = p; p += 8388608;               // v^T (b*h, v, n)

  k_cast_h<<<dim3(2048), dim3(256), 0, stream>>>(x, xf, 8388608);

  k_transpose_h4<<<dim3(64, 64, 4), dim3(32, 8), 0, stream>>>(
      wq, wk, wv, wo, wt3, wt3 + 4194304, wt3 + 8388608, wto);

  // merged q|k|v projection: C (4096 x 6144), 128^2 tiles, double-buffered
  k_gemm_db<0><<<dim3(48, 32), dim3(256), 0, stream>>>(xf, wt3, qkv, 6144);
  k_transpose_v<<<dim3(4, 64, 32), dim3(32, 8), 0, stream>>>(qkv, vtf);

  // y written into the (now dead) x plane
  k_attn1<<<dim3(32, 16), dim3(256), 0, stream>>>(qkv, vtf, nm, rs, xf);

  k_gemm_db<1><<<dim3(16, 32), dim3(256), 0, stream>>>(xf, wto, d_out, 2048);
}